// Round 12
// baseline (282.156 us; speedup 1.0000x reference)
//
#include <hip/hip_runtime.h>

// GraphConv: out[t] += input[s] * (esgn*enorm), 3.2M edges, 100K nodes, D=32 fp32.
// Round 12: partition output stage rewritten slot-linear + binary-search bucket
// lookup -> coalesced run writes (was: lane-serial 8B scattered stores, one
// line-txn per lane per instr). Rest of R11 pipeline unchanged:
//   bhist(LDS) -> bscan -> partition -> nodesort2 (fused hist/scan/scatter)
//   -> seg_accum (atomic-free, 12.5K waves, ~70us = near gather ceiling).

#define NB   256
#define MAXK 256          // max buckets (span 512 -> n_nodes <= 131072)
#define SPAN_SHIFT 9
#define SPAN 512
#define PT   7680         // partition tile edges; srec = 60KB LDS

// Bucket-level histogram: LDS counters, one global atomic per bucket/block.
__global__ __launch_bounds__(NB) void bhist_kernel(
    const int* __restrict__ tidx, int* __restrict__ bcnt, int n_edges)
{
    __shared__ int lh[MAXK];
    for (int i = threadIdx.x; i < MAXK; i += NB) lh[i] = 0;
    __syncthreads();
    int stride = gridDim.x * NB;
    for (int e = blockIdx.x * NB + threadIdx.x; e < n_edges; e += stride)
        atomicAdd(&lh[tidx[e] >> SPAN_SHIFT], 1);
    __syncthreads();
    for (int i = threadIdx.x; i < MAXK; i += NB)
        if (lh[i]) atomicAdd(&bcnt[i], lh[i]);
}

// Exclusive scan over MAXK bucket counts -> bbase[0..MAXK], bcur=bbase.
__global__ __launch_bounds__(MAXK) void bscan_kernel(
    const int* __restrict__ bcnt, int* __restrict__ bbase, int* __restrict__ bcur)
{
    __shared__ int part[MAXK];
    int t = threadIdx.x;
    int c = bcnt[t];
    part[t] = c;
    __syncthreads();
    for (int off = 1; off < MAXK; off <<= 1) {
        int v = (t >= off) ? part[t - off] : 0;
        __syncthreads();
        part[t] += v;
        __syncthreads();
    }
    int excl = part[t] - c;
    bbase[t] = excl;
    bcur[t] = excl;
    if (t == MAXK - 1) bbase[MAXK] = part[MAXK - 1];
}

// Tile-local bucket sort in LDS; output stage is slot-linear + binary search
// so global run writes are coalesced.
__global__ __launch_bounds__(NB) void partition_kernel(
    const int* __restrict__ sidx, const int* __restrict__ tidx,
    const float* __restrict__ enorm, const float* __restrict__ esgn,
    int* __restrict__ bcur, int2* __restrict__ recs, int n_edges)
{
    __shared__ int2 srec[PT];              // 60 KB
    __shared__ int lh[MAXK];
    __shared__ int lbase[MAXK];
    __shared__ int lcur[MAXK];
    __shared__ int gb[MAXK];
    int t = threadIdx.x;
    lh[t] = 0;
    __syncthreads();

    size_t tb = (size_t)blockIdx.x * PT;
    for (int j = 0; j < PT / NB; ++j) {
        int e = (int)tb + j * NB + t;
        if (e < n_edges) atomicAdd(&lh[tidx[e] >> SPAN_SHIFT], 1);
    }
    __syncthreads();
    int c = lh[t];
    lbase[t] = c;
    __syncthreads();
    for (int off = 1; off < MAXK; off <<= 1) {
        int v = (t >= off) ? lbase[t - off] : 0;
        __syncthreads();
        lbase[t] += v;
        __syncthreads();
    }
    int excl = lbase[t] - c;
    __syncthreads();
    lbase[t] = excl;
    lcur[t] = excl;
    if (c > 0) gb[t] = atomicAdd(&bcur[t], c);
    __syncthreads();
    for (int j = 0; j < PT / NB; ++j) {
        int e = (int)tb + j * NB + t;
        if (e < n_edges) {
            int tn = tidx[e];
            int b = tn >> SPAN_SHIFT;
            unsigned rec = ((unsigned)sidx[e] << SPAN_SHIFT) | (unsigned)(tn & (SPAN - 1));
            float w = enorm[e] * esgn[e];
            int p = atomicAdd(&lcur[b], 1);
            srec[p] = make_int2((int)rec, __float_as_int(w));
        }
    }
    __syncthreads();
    // coalesced copy-out: linear over tile slots; binary search for bucket.
    int tilecnt = lbase[MAXK - 1] + lh[MAXK - 1];
    for (int i = t; i < tilecnt; i += NB) {
        int lo = 0, hi = MAXK - 1;
        while (lo < hi) {                   // largest b with lbase[b] <= i
            int mid = (lo + hi + 1) >> 1;
            if (lbase[mid] <= i) lo = mid; else hi = mid - 1;
        }
        recs[gb[lo] + (i - lbase[lo])] = srec[i];
    }
}

// Fused per-bucket node hist + scan + scatter (recs L2-hot, two passes).
__global__ __launch_bounds__(1024) void nodesort2_kernel(
    const int2* __restrict__ recs, const int* __restrict__ bbase,
    int* __restrict__ nodeoff, int2* __restrict__ sorted, int n_nodes, int K)
{
    __shared__ int lcnt[SPAN];
    __shared__ int lpart[SPAN];
    __shared__ int lcur[SPAN];
    int b = blockIdx.x;
    int t = threadIdx.x;
    int base_node = b << SPAN_SHIFT;
    int bstart = bbase[b], bend = bbase[b + 1];

    for (int i = t; i < SPAN; i += 1024) lcnt[i] = 0;
    __syncthreads();
    for (int i = bstart + t; i < bend; i += 1024)
        atomicAdd(&lcnt[recs[i].x & (SPAN - 1)], 1);
    __syncthreads();
    int c = (t < SPAN) ? lcnt[t] : 0;
    if (t < SPAN) lpart[t] = c;
    __syncthreads();
    for (int off = 1; off < SPAN; off <<= 1) {
        int v = (t < SPAN && t >= off) ? lpart[t - off] : 0;
        __syncthreads();
        if (t < SPAN) lpart[t] += v;
        __syncthreads();
    }
    if (t < SPAN) {
        int excl = lpart[t] - c;
        int node = base_node + t;
        int gpos = bstart + excl;
        lcur[t] = gpos;
        if (node < n_nodes) nodeoff[node] = gpos;
    }
    if (b == K - 1 && t == 0) nodeoff[n_nodes] = bend;
    __syncthreads();
    for (int i = bstart + t; i < bend; i += 1024) {
        int2 r = recs[i];
        int pos = atomicAdd(&lcur[r.x & (SPAN - 1)], 1);
        sorted[pos] = r;
    }
}

// Segmented accumulate: 8 lanes per node, float4 per lane; no atomics.
__global__ __launch_bounds__(NB) void seg_accum(
    const float* __restrict__ input, const int2* __restrict__ sorted,
    const int* __restrict__ nodeoff, float* __restrict__ out, int n_nodes)
{
    int n = blockIdx.x * 32 + (threadIdx.x >> 3);
    int lane = threadIdx.x & 7;
    if (n >= n_nodes) return;
    int beg = nodeoff[n], end = nodeoff[n + 1];
    float4 acc = make_float4(0.f, 0.f, 0.f, 0.f);
    for (int i = beg; i < end; ++i) {
        int2 r = sorted[i];                       // broadcast within group
        float w = __int_as_float(r.y);
        int s = (int)(((unsigned)r.x) >> SPAN_SHIFT);
        float4 v = ((const float4*)(input + (size_t)s * 32))[lane];
        acc.x = fmaf(w, v.x, acc.x);
        acc.y = fmaf(w, v.y, acc.y);
        acc.z = fmaf(w, v.z, acc.z);
        acc.w = fmaf(w, v.w, acc.w);
    }
    ((float4*)(out + (size_t)n * 32))[lane] = acc;
}

// Last-resort fallback (R3): direct atomic scatter.
__global__ __launch_bounds__(NB) void graphconv_scatter(
    const float* __restrict__ input, const int* __restrict__ sidx,
    const int* __restrict__ tidx, const float* __restrict__ enorm,
    const float* __restrict__ esgn, float* __restrict__ out, int n_edges)
{
    int t = blockIdx.x * NB + threadIdx.x;
    int e = t >> 3;
    int sub = t & 7;
    if (e >= n_edges) return;
    int s = sidx[e];
    int d = tidx[e];
    float w = enorm[e] * esgn[e];
    const float4* src = (const float4*)(input + (size_t)s * 32);
    float4 v = src[sub];
    float* op = out + (size_t)d * 32 + sub * 4;
    atomicAdd(op + 0, v.x * w);
    atomicAdd(op + 1, v.y * w);
    atomicAdd(op + 2, v.z * w);
    atomicAdd(op + 3, v.w * w);
}

extern "C" void kernel_launch(void* const* d_in, const int* in_sizes, int n_in,
                              void* d_out, int out_size, void* d_ws, size_t ws_size,
                              hipStream_t stream) {
    const float* input = (const float*)d_in[0];
    const int*   eidx  = (const int*)d_in[1];   // int64 in reference -> int32 here
    const float* enorm = (const float*)d_in[2];
    const float* esgn  = (const float*)d_in[3];
    float*       out   = (float*)d_out;

    int n_edges = in_sizes[1] / 2;             // eidx is (2, n_edges)
    int n_nodes = in_sizes[0] / 32;            // input is (n_nodes, 32)
    const int* sidx = eidx;
    const int* tidx = eidx + n_edges;

    int K = (n_nodes + SPAN - 1) >> SPAN_SHIFT;   // 196

    // Workspace: sorted[E int2] | recs[E int2] | nodeoff[n+1]
    //            | bcnt[MAXK] | bbase[MAXK+1] | bcur[MAXK]
    size_t need = (size_t)n_edges * 16 +
                  ((size_t)n_nodes + 1 + 3 * MAXK + 1) * 4;

    if (ws_size >= need && K <= MAXK) {
        int2* sorted  = (int2*)d_ws;
        int2* recs    = sorted + n_edges;
        int*  nodeoff = (int*)(recs + n_edges);
        int*  bcnt    = nodeoff + (n_nodes + 1);
        int*  bbase   = bcnt + MAXK;
        int*  bcur    = bbase + (MAXK + 1);

        hipMemsetAsync(bcnt, 0, MAXK * sizeof(int), stream);

        bhist_kernel    <<<1024, NB,   0, stream>>>(tidx, bcnt, n_edges);
        bscan_kernel    <<<1,    MAXK, 0, stream>>>(bcnt, bbase, bcur);
        int pg = (n_edges + PT - 1) / PT;
        partition_kernel<<<pg,   NB,   0, stream>>>(sidx, tidx, enorm, esgn,
                                                    bcur, recs, n_edges);
        nodesort2_kernel<<<K,    1024, 0, stream>>>(recs, bbase, nodeoff,
                                                    sorted, n_nodes, K);
        int ag = (n_nodes + 31) / 32;
        seg_accum       <<<ag,   NB,   0, stream>>>(input, sorted, nodeoff,
                                                    out, n_nodes);
    } else {
        hipMemsetAsync(d_out, 0, (size_t)out_size * sizeof(float), stream);
        size_t threads_total = (size_t)n_edges * 8;
        int grid = (int)((threads_total + NB - 1) / NB);
        graphconv_scatter<<<grid, NB, 0, stream>>>(input, sidx, tidx, enorm, esgn,
                                                   out, n_edges);
    }
}